// Round 1
// baseline (315.067 us; speedup 1.0000x reference)
//
#include <hip/hip_runtime.h>

typedef unsigned short u16;
typedef __bf16 bf16x8 __attribute__((ext_vector_type(8)));
typedef float f32x4 __attribute__((ext_vector_type(4)));

// Problem constants
#define M_DIM 8192      // BATCH*SEQ
#define K_DIM 1024      // MAX_D_IN
#define N_EFF 3072      // nonzero output columns
#define N_FULL 6144     // MAX_D_OUT
#define BM 128
#define BN 128
#define BK 32

// ---- helpers ----------------------------------------------------------------
__device__ __forceinline__ u16 f2bf_rne(float f) {
    unsigned u = __float_as_uint(f);
    u += 0x7fffu + ((u >> 16) & 1u);
    return (u16)(u >> 16);
}

__device__ __forceinline__ void gld_lds16(const u16* g, u16* l) {
    // async global->LDS, 16B per lane. LDS dest is wave-uniform base + lane*16;
    // our chunk indexing is arranged so lane-order == contiguous LDS order.
    __builtin_amdgcn_global_load_lds(
        (const __attribute__((address_space(1))) unsigned int*)g,
        (__attribute__((address_space(3))) unsigned int*)l, 16, 0, 0);
}

// ---- prep: x fp32 -> bf16 ---------------------------------------------------
__global__ void cvt_x(const float* __restrict__ in, u16* __restrict__ out, int n8) {
    int i = blockIdx.x * 256 + threadIdx.x;
    if (i >= n8) return;
    const float4* p = reinterpret_cast<const float4*>(in) + 2 * (size_t)i;
    float4 a = p[0], b = p[1];
    union { u16 h[8]; uint4 v; } r;
    float vals[8] = {a.x, a.y, a.z, a.w, b.x, b.y, b.z, b.w};
#pragma unroll
    for (int j = 0; j < 8; j++) r.h[j] = f2bf_rne(vals[j]);
    reinterpret_cast<uint4*>(out)[i] = r.v;
}

// ---- prep: W_mix = W * M(o,i) -> bf16 (rows [0,3072) only) ------------------
__global__ void prep_w(const float* __restrict__ W, const float* __restrict__ wt,
                       u16* __restrict__ Wm, int n8) {
    int i = blockIdx.x * 256 + threadIdx.x;
    if (i >= n8) return;
    float w01 = wt[0] + wt[1], w23 = wt[2] + wt[3], w45 = wt[4] + wt[5];
    int o = i >> 7;              // row (128 chunks of 8 per 1024-wide row)
    int ib = (i & 127) * 8;      // column base; 512/768 are multiples of 8
    float s = w45;
    if (o < 2304 && ib < 768) s += w23;
    if (o < 1536 && ib < 512) s += w01;
    const float4* p = reinterpret_cast<const float4*>(W) + 2 * (size_t)i;
    float4 a = p[0], b = p[1];
    union { u16 h[8]; uint4 v; } r;
    float vals[8] = {a.x, a.y, a.z, a.w, b.x, b.y, b.z, b.w};
#pragma unroll
    for (int j = 0; j < 8; j++) r.h[j] = f2bf_rne(vals[j] * s);
    reinterpret_cast<uint4*>(Wm)[i] = r.v;
}

// ---- prep: b_mix ------------------------------------------------------------
__global__ void prep_b(const float* __restrict__ b, const float* __restrict__ wt,
                       float* __restrict__ bm) {
    int o = blockIdx.x * 256 + threadIdx.x;
    if (o >= N_EFF) return;
    float w01 = wt[0] + wt[1], w23 = wt[2] + wt[3], w45 = wt[4] + wt[5];
    float s = w45 + (o < 2304 ? w23 : 0.f) + (o < 1536 ? w01 : 0.f);
    bm[o] = b[o] * s;
}

// ---- GEMM: C[m,n] = sum_k A[m,k]*B[n,k] + bias[n]; also zero-fills n+3072 ---
// m97 recipe: 128x128 block tile, BK=32, 4 waves (2x2), each wave 64x64 via
// 4x4 grid of 16x16x32 bf16 MFMAs, global_load_lds width=16 staging.
__global__ __launch_bounds__(256, 2) void gemm_bt(
    const u16* __restrict__ A,   // [8192][1024] bf16
    const u16* __restrict__ B,   // [3072][1024] bf16 (row = output col)
    const float* __restrict__ bias,
    float* __restrict__ C)       // [8192][6144] fp32
{
    __shared__ u16 As[BM * BK];  // 8 KB
    __shared__ u16 Bs[BN * BK];  // 8 KB

    const int tid  = threadIdx.x;
    const int bx   = blockIdx.x;   // N tile 0..23
    const int by   = blockIdx.y;   // M tile 0..63
    const int lane = tid & 63;
    const int wv   = tid >> 6;
    const int wm   = (wv >> 1) * 64;  // wave row offset in tile
    const int wn   = (wv & 1) * 64;   // wave col offset in tile

    f32x4 acc[4][4] = {};

    const u16* Ag = A + (size_t)(by * BM) * K_DIM;
    const u16* Bg = B + (size_t)(bx * BN) * K_DIM;

    const int kq  = (lane >> 4) * 8;  // k offset of this lane's fragment
    const int r16 = lane & 15;

    for (int kt = 0; kt < K_DIM; kt += BK) {
        __syncthreads();  // protect previous iteration's LDS reads
#pragma unroll
        for (int s = 0; s < 2; s++) {
            int c = s * 256 + tid;            // chunk index, 16B each
            int row = c >> 2, kc = (c & 3) * 8;
            gld_lds16(Ag + (size_t)row * K_DIM + kt + kc, &As[c * 8]);
            gld_lds16(Bg + (size_t)row * K_DIM + kt + kc, &Bs[c * 8]);
        }
        __syncthreads();  // drains vmcnt before reads

        bf16x8 af[4], bf[4];
#pragma unroll
        for (int t = 0; t < 4; t++) {
            af[t] = *reinterpret_cast<const bf16x8*>(&As[(wm + t * 16 + r16) * BK + kq]);
            bf[t] = *reinterpret_cast<const bf16x8*>(&Bs[(wn + t * 16 + r16) * BK + kq]);
        }
#pragma unroll
        for (int tm = 0; tm < 4; tm++)
#pragma unroll
            for (int tn = 0; tn < 4; tn++)
                acc[tm][tn] = __builtin_amdgcn_mfma_f32_16x16x32_bf16(
                    af[tm], bf[tn], acc[tm][tn], 0, 0, 0);
    }

    // Epilogue: C/D layout col=lane&15 (n), row=(lane>>4)*4+reg (m).
    const int m0 = by * BM + wm + (lane >> 4) * 4;
    const int n0 = bx * BN + wn + (lane & 15);
#pragma unroll
    for (int tn = 0; tn < 4; tn++) {
        int n = n0 + tn * 16;
        float bv = bias[n];
#pragma unroll
        for (int tm = 0; tm < 4; tm++) {
            int m = m0 + tm * 16;
#pragma unroll
            for (int r = 0; r < 4; r++)
                C[(size_t)(m + r) * N_FULL + n] = acc[tm][tn][r] + bv;
        }
    }

    // Zero-fill the mirror tile at columns [3072+bx*128, +128): exact zeros in ref.
    const float4 z = make_float4(0.f, 0.f, 0.f, 0.f);
#pragma unroll
    for (int it = 0; it < 16; it++) {
        int lin = it * 256 + tid;        // 0..4095 -> 128 rows x 32 float4
        int row = lin >> 5;
        int c4  = (lin & 31) * 4;
        reinterpret_cast<float4*>(
            &C[(size_t)(by * BM + row) * N_FULL + N_EFF + bx * BN + c4])[0] = z;
    }
}

// ---- launch -----------------------------------------------------------------
extern "C" void kernel_launch(void* const* d_in, const int* in_sizes, int n_in,
                              void* d_out, int out_size, void* d_ws, size_t ws_size,
                              hipStream_t stream) {
    const float* x   = (const float*)d_in[0];  // [8,1024,1024]
    const float* wts = (const float*)d_in[1];  // [6]
    const float* W   = (const float*)d_in[2];  // [6144,1024]
    const float* b   = (const float*)d_in[3];  // [6144]
    float* out = (float*)d_out;                // [8192,6144]

    // workspace: xb 16 MB | Wm 6 MB | bm 12 KB  (total ~22.1 MB)
    u16*   xb = (u16*)d_ws;
    u16*   Wm = (u16*)((char*)d_ws + 16777216);
    float* bm = (float*)((char*)d_ws + 23068672);

    cvt_x <<<4096, 256, 0, stream>>>(x, xb, M_DIM * K_DIM / 8);   // 1,048,576 chunks
    prep_w<<<1536, 256, 0, stream>>>(W, wts, Wm, N_EFF * K_DIM / 8); // 393,216 chunks
    prep_b<<<12,   256, 0, stream>>>(b, wts, bm);
    gemm_bt<<<dim3(N_EFF / BN, M_DIM / BM), 256, 0, stream>>>(xb, Wm, bm, out);
}

// Round 3
// 284.403 us; speedup vs baseline: 1.1078x; 1.1078x over previous
//
#include <hip/hip_runtime.h>

typedef unsigned short u16;
typedef __bf16 bf16x8 __attribute__((ext_vector_type(8)));
typedef float f32x4 __attribute__((ext_vector_type(4)));

// Problem constants
#define M_DIM 8192      // BATCH*SEQ
#define K_DIM 1024      // MAX_D_IN
#define N_EFF 3072      // nonzero output columns
#define N_FULL 6144     // MAX_D_OUT
#define BM 128
#define BN 128
#define BK 32           // per sub-tile; 2 sub-tiles staged per barrier

// ---- helpers ----------------------------------------------------------------
__device__ __forceinline__ u16 f2bf_rne(float f) {
    unsigned u = __float_as_uint(f);
    u += 0x7fffu + ((u >> 16) & 1u);
    return (u16)(u >> 16);
}

__device__ __forceinline__ void gld_lds16(const u16* g, u16* l) {
    // async global->LDS, 16B per lane; LDS dest = wave-uniform base + lane*16,
    // our chunk indexing keeps lane-order == contiguous LDS order.
    __builtin_amdgcn_global_load_lds(
        (const __attribute__((address_space(1))) unsigned int*)g,
        (__attribute__((address_space(3))) unsigned int*)l, 16, 0, 0);
}

// ---- prep: x fp32 -> bf16 ---------------------------------------------------
__global__ void cvt_x(const float* __restrict__ in, u16* __restrict__ out, int n8) {
    int i = blockIdx.x * 256 + threadIdx.x;
    if (i >= n8) return;
    const float4* p = reinterpret_cast<const float4*>(in) + 2 * (size_t)i;
    float4 a = p[0], b = p[1];
    union { u16 h[8]; uint4 v; } r;
    float vals[8] = {a.x, a.y, a.z, a.w, b.x, b.y, b.z, b.w};
#pragma unroll
    for (int j = 0; j < 8; j++) r.h[j] = f2bf_rne(vals[j]);
    reinterpret_cast<uint4*>(out)[i] = r.v;
}

// ---- prep: W_mix = W * M(o,i) -> bf16 (rows [0,3072) only) ------------------
__global__ void prep_w(const float* __restrict__ W, const float* __restrict__ wt,
                       u16* __restrict__ Wm, int n8) {
    int i = blockIdx.x * 256 + threadIdx.x;
    if (i >= n8) return;
    float w01 = wt[0] + wt[1], w23 = wt[2] + wt[3], w45 = wt[4] + wt[5];
    int o = i >> 7;              // row (128 chunks of 8 per 1024-wide row)
    int ib = (i & 127) * 8;      // column base; 512/768 are multiples of 8
    float s = w45;
    if (o < 2304 && ib < 768) s += w23;
    if (o < 1536 && ib < 512) s += w01;
    const float4* p = reinterpret_cast<const float4*>(W) + 2 * (size_t)i;
    float4 a = p[0], b = p[1];
    union { u16 h[8]; uint4 v; } r;
    float vals[8] = {a.x, a.y, a.z, a.w, b.x, b.y, b.z, b.w};
#pragma unroll
    for (int j = 0; j < 8; j++) r.h[j] = f2bf_rne(vals[j] * s);
    reinterpret_cast<uint4*>(Wm)[i] = r.v;
}

// ---- GEMM: C[m,n] = sum_k A[m,k]*B[n,k] + b[n]*s(n); zero-fills n+3072 ------
// m97 recipe, but 2x BK=32 sub-tiles staged per barrier (16 barriers, not 32).
// LDS 32 KB -> still 3 blocks/CU at VGPR<=168 (launch_bounds(256,3)).
__global__ __launch_bounds__(256, 3) void gemm_bt(
    const u16* __restrict__ A,   // [8192][1024] bf16
    const u16* __restrict__ B,   // [3072][1024] bf16 (row = output col)
    const float* __restrict__ bias, // raw b[6144] fp32
    const float* __restrict__ wt,   // weights[6]
    float* __restrict__ C)       // [8192][6144] fp32
{
    __shared__ u16 As[2 * BM * BK];  // 16 KB: sub-tile st at offset st*4096
    __shared__ u16 Bs[2 * BN * BK];  // 16 KB

    const int tid  = threadIdx.x;
    const int bx   = blockIdx.x;   // N tile 0..23
    const int by   = blockIdx.y;   // M tile 0..63
    const int lane = tid & 63;
    const int wv   = tid >> 6;
    const int wm   = (wv >> 1) * 64;  // wave row offset in tile
    const int wn   = (wv & 1) * 64;   // wave col offset in tile

    f32x4 acc[4][4] = {};

    const u16* Ag = A + (size_t)(by * BM) * K_DIM;
    const u16* Bg = B + (size_t)(bx * BN) * K_DIM;

    const int kq  = (lane >> 4) * 8;  // k offset of this lane's fragment
    const int r16 = lane & 15;

    for (int kt = 0; kt < K_DIM; kt += 2 * BK) {
        __syncthreads();  // protect previous iteration's LDS reads
#pragma unroll
        for (int u = 0; u < 4; u++) {
            int c  = u * 256 + tid;        // chunk index 0..1023, 16B each
            int st = c >> 9;               // sub-tile 0/1
            int c2 = c & 511;
            int row = c2 >> 2, kc = (c2 & 3) * 8;
            size_t goff = (size_t)row * K_DIM + kt + st * BK + kc;
            gld_lds16(Ag + goff, &As[c * 8]);
            gld_lds16(Bg + goff, &Bs[c * 8]);
        }
        __syncthreads();  // drains vmcnt before reads

#pragma unroll
        for (int st = 0; st < 2; st++) {
            bf16x8 af[4], bf[4];
#pragma unroll
            for (int t = 0; t < 4; t++) {
                af[t] = *reinterpret_cast<const bf16x8*>(
                    &As[st * 4096 + (wm + t * 16 + r16) * BK + kq]);
                bf[t] = *reinterpret_cast<const bf16x8*>(
                    &Bs[st * 4096 + (wn + t * 16 + r16) * BK + kq]);
            }
#pragma unroll
            for (int tm = 0; tm < 4; tm++)
#pragma unroll
                for (int tn = 0; tn < 4; tn++)
                    acc[tm][tn] = __builtin_amdgcn_mfma_f32_16x16x32_bf16(
                        af[tm], bf[tn], acc[tm][tn], 0, 0, 0);
        }
    }

    // Fused bias: s(n) = w45 + (n<2304)*w23 + (n<1536)*w01
    const float w01 = wt[0] + wt[1], w23 = wt[2] + wt[3], w45 = wt[4] + wt[5];

    // Epilogue: C/D layout col=lane&15 (n), row=(lane>>4)*4+reg (m).
    const int m0 = by * BM + wm + (lane >> 4) * 4;
    const int n0 = bx * BN + wn + (lane & 15);
#pragma unroll
    for (int tn = 0; tn < 4; tn++) {
        int n = n0 + tn * 16;
        float s = w45 + (n < 2304 ? w23 : 0.f) + (n < 1536 ? w01 : 0.f);
        float bv = bias[n] * s;
#pragma unroll
        for (int tm = 0; tm < 4; tm++) {
            int m = m0 + tm * 16;
#pragma unroll
            for (int r = 0; r < 4; r++)
                __builtin_nontemporal_store(acc[tm][tn][r] + bv,
                    &C[(size_t)(m + r) * N_FULL + n]);
        }
    }

    // Zero-fill the mirror tile at columns [3072+bx*128, +128): exact zeros in ref.
    const f32x4 z = {0.f, 0.f, 0.f, 0.f};
#pragma unroll
    for (int it = 0; it < 16; it++) {
        int lin = it * 256 + tid;        // 0..4095 -> 128 rows x 32 float4
        int row = lin >> 5;
        int c4  = (lin & 31) * 4;
        __builtin_nontemporal_store(z, reinterpret_cast<f32x4*>(
            &C[(size_t)(by * BM + row) * N_FULL + N_EFF + bx * BN + c4]));
    }
}

// ---- launch -----------------------------------------------------------------
extern "C" void kernel_launch(void* const* d_in, const int* in_sizes, int n_in,
                              void* d_out, int out_size, void* d_ws, size_t ws_size,
                              hipStream_t stream) {
    const float* x   = (const float*)d_in[0];  // [8,1024,1024]
    const float* wts = (const float*)d_in[1];  // [6]
    const float* W   = (const float*)d_in[2];  // [6144,1024]
    const float* b   = (const float*)d_in[3];  // [6144]
    float* out = (float*)d_out;                // [8192,6144]

    // workspace: xb 16 MB | Wm 6 MB
    u16* xb = (u16*)d_ws;
    u16* Wm = (u16*)((char*)d_ws + 16777216);

    cvt_x <<<4096, 256, 0, stream>>>(x, xb, M_DIM * K_DIM / 8);      // 1,048,576 chunks
    prep_w<<<1536, 256, 0, stream>>>(W, wts, Wm, N_EFF * K_DIM / 8); // 393,216 chunks
    gemm_bt<<<dim3(N_EFF / BN, M_DIM / BM), 256, 0, stream>>>(xb, Wm, b, wts, out);
}